// Round 6
// baseline (634.924 us; speedup 1.0000x reference)
//
#include <hip/hip_runtime.h>

typedef unsigned short ushort_t;
typedef unsigned int uint_t;
typedef __bf16 bf16x8 __attribute__((ext_vector_type(8)));
typedef float floatx4 __attribute__((ext_vector_type(4)));

#define T_TOK 1024
#define HID 2880
#define NH 64
#define KV 8
#define HD 64
#define INTER 2880
#define QKV_DIM 5120   // HD*(NH+2*KV)
#define O_DIM 4096     // NH*HD

typedef __attribute__((address_space(1))) const uint_t glb_u32;
typedef __attribute__((address_space(3))) uint_t lds_u32;

__device__ __forceinline__ float b2f(ushort_t u) {
    uint_t i = ((uint_t)u) << 16;
    return __builtin_bit_cast(float, i);
}
__device__ __forceinline__ ushort_t f2b(float f) {
    uint_t i = __builtin_bit_cast(uint_t, f);
    uint_t r = i + 0x7FFFu + ((i >> 16) & 1u);
    return (ushort_t)(r >> 16);
}
__device__ __forceinline__ uint4 ld16(const void* p) { uint4 v; __builtin_memcpy(&v, p, 16); return v; }
__device__ __forceinline__ void st16(void* p, uint4 v) { __builtin_memcpy(p, &v, 16); }
__device__ __forceinline__ float4 ld16f(const void* p) { float4 v; __builtin_memcpy(&v, p, 16); return v; }
__device__ __forceinline__ bf16x8 ldfrag(const void* p) { bf16x8 v; __builtin_memcpy(&v, p, 16); return v; }
// native bf16 casts -> v_cvt_pk_bf16_f32 (RNE, bit-identical to the f2b trick)
__device__ __forceinline__ void cvt8st(void* lds, float4 a, float4 b) {
    __bf16 o[8] = {(__bf16)a.x, (__bf16)a.y, (__bf16)a.z, (__bf16)a.w,
                   (__bf16)b.x, (__bf16)b.y, (__bf16)b.z, (__bf16)b.w};
    __builtin_memcpy(lds, o, 16);
}

// ---------------- RMSNorm: f32 in -> bf16 out ------------------------------
__global__ __launch_bounds__(256) void rmsnorm_f2b(
    const float* __restrict__ x, const float* __restrict__ scale,
    ushort_t* __restrict__ out)
{
    const int row = blockIdx.x;
    const int tid = threadIdx.x;
    const float* xr = x + (size_t)row * HID;
    float ss = 0.f;
    for (int i = tid; i < HID / 4; i += 256) {
        float4 v = ld16f(xr + i * 4);
        ss += v.x * v.x + v.y * v.y + v.z * v.z + v.w * v.w;
    }
    #pragma unroll
    for (int m = 32; m >= 1; m >>= 1) ss += __shfl_xor(ss, m, 64);
    __shared__ float red[4];
    if ((tid & 63) == 0) red[tid >> 6] = ss;
    __syncthreads();
    float rstd = rsqrtf((red[0] + red[1] + red[2] + red[3]) / (float)HID + 1e-5f);
    for (int i = tid; i < HID / 8; i += 256) {
        float4 a = ld16f(xr + i * 8);
        float4 b = ld16f(xr + i * 8 + 4);
        float4 sa = ld16f(scale + i * 8);
        float4 sb = ld16f(scale + i * 8 + 4);
        cvt8st(out + (size_t)row * HID + i * 8,
               make_float4(a.x * rstd * sa.x, a.y * rstd * sa.y, a.z * rstd * sa.z, a.w * rstd * sa.w),
               make_float4(b.x * rstd * sb.x, b.y * rstd * sb.y, b.z * rstd * sb.z, b.w * rstd * sb.w));
    }
}

// ---------------- GEMM: C[M,N] = A_bf16[M,K] @ B_f32[N,K]^T + bias ---------
// BM=64, BN=64, BK=64, 256 threads (2x2 waves, wave tile 32x32).
// R4-proven mechanics (BK=64, 128B LDS rows, row&7 XOR swizzle, f32 B
// staged through regs, counted-vmcnt double buffer) with BM halved:
// grids are 1280-1440 blocks (~5 blocks/CU vs R4's 2) and LDS is 32 KB
// (5 blocks resident). Concurrency was grid-capped at BM=128 -- 5
// independent block pipelines overlap the per-step HBM/L2 miss latency.
// N-MAJOR tile order (B panel L2 sharing) + bijective XCD chunking.
// Optional split-K (gridDim.y==2): z=1 writes f32 partial to scratch.
__global__ __launch_bounds__(256) void gemm_bt(
    const ushort_t* __restrict__ A, const float* __restrict__ B,
    const float* __restrict__ bias, const float* residual,
    void* C, int out_f32, float* __restrict__ scratch,
    int M, int N, int K)
{
    __shared__ ushort_t As[2][64 * 64];   // 2 x 8 KB, rows of 128B
    __shared__ ushort_t Bs[2][64 * 64];   // 2 x 8 KB, rows of 128B
    const int tid = threadIdx.x;
    const int lane = tid & 63, wave = tid >> 6;
    const int l15 = lane & 15, quad = lane >> 4;

    // XCD-aware bijective remap: XCD k owns a contiguous chunk of flats.
    const int nbm = M >> 6;
    int flat = (int)blockIdx.x;
    const int cpx = (int)gridDim.x >> 3;
    flat = (flat & 7) * cpx + (flat >> 3);
    // n-major decode: consecutive flats share the B panel (n0), vary m0.
    const int m0 = (flat % nbm) * 64;
    const int n0 = (flat / nbm) * 64;

    const int wm = (wave >> 1) * 32, wn = (wave & 1) * 32;

    // split-K bounds (by 64-wide K-steps; handles nk odd)
    const int z = (int)blockIdx.y;
    const int nk_all = K >> 6;
    const int nk0 = (nk_all + 1) >> 1;
    const int kbeg = (gridDim.y > 1 && z) ? (nk0 << 6) : 0;
    const int nk = (gridDim.y > 1) ? (z ? nk_all - nk0 : nk0) : nk_all;

    // A glds (2 instr/wave, 32 rows each): lane l of wave w, instr q ->
    // LDS row q*32 + w*8 + (l>>3), slot l&7. row&7 == l>>3, so the
    // pre-swizzled global slot is constant per lane:
    const int arow = wave * 8 + (lane >> 3);               // + q*32
    const int aslot = (lane & 7) ^ (lane >> 3);
    const ushort_t* Abase = A + (size_t)(m0 + arow) * K + kbeg + aslot * 8;

    // B staging: thread t -> row t>>2, k-slots (t&3) and (t&3)+4
    const int brow = tid >> 2;
    const int kb = (tid & 3) * 8;
    const int sa = (tid & 3) ^ (brow & 7);
    const int sb = ((tid & 3) + 4) ^ (brow & 7);
    const float* Bbase = B + (size_t)(n0 + brow) * K + kbeg;

    floatx4 acc[2][2] = {};

    // ---- prologue: stage K-step 0 into buffer 0
    {
        float4 f0 = ld16f(Bbase + kb);
        float4 f1 = ld16f(Bbase + kb + 4);
        float4 f2 = ld16f(Bbase + kb + 32);
        float4 f3 = ld16f(Bbase + kb + 36);
        #pragma unroll
        for (int q = 0; q < 2; q++)
            __builtin_amdgcn_global_load_lds(
                (glb_u32*)(Abase + (size_t)(q * 32) * K),
                (lds_u32*)(&As[0][(q * 32 + wave * 8) * 64]), 16, 0, 0);
        cvt8st(&Bs[0][brow * 64 + sa * 8], f0, f1);
        cvt8st(&Bs[0][brow * 64 + sb * 8], f2, f3);
    }
    // at loop entry: outstanding vmem = 2 glds (B loads retired by cvt wait)

    int cur = 0;
    for (int kt = 0; kt < nk; ++kt) {
        const int nxt = cur ^ 1;
        const bool pre = (kt + 1 < nk);
        float4 f0, f1, f2, f3;
        if (pre) {
            const int k1 = (kt + 1) << 6;
            f0 = ld16f(Bbase + k1 + kb);
            f1 = ld16f(Bbase + k1 + kb + 4);
            f2 = ld16f(Bbase + k1 + kb + 32);
            f3 = ld16f(Bbase + k1 + kb + 36);
            #pragma unroll
            for (int q = 0; q < 2; q++)
                __builtin_amdgcn_global_load_lds(
                    (glb_u32*)(Abase + (size_t)(q * 32) * K + k1),
                    (lds_u32*)(&As[nxt][(q * 32 + wave * 8) * 64]), 16, 0, 0);
            // wait: all PREVIOUS-tile loads retired; this tile's 6 stay in flight
            asm volatile("s_waitcnt vmcnt(6)" ::: "memory");
        } else {
            asm volatile("s_waitcnt vmcnt(0)" ::: "memory");
        }
        // prev iteration's Bs[cur] ds_writes globally visible after barrier
        asm volatile("s_waitcnt lgkmcnt(0)" ::: "memory");
        __builtin_amdgcn_s_barrier();
        __builtin_amdgcn_sched_barrier(0);   // pin: no ds_read above barrier

        // ---- compute on buffer cur (loads for nxt in flight)
        #pragma unroll
        for (int c = 0; c < 2; c++) {
            bf16x8 af[2], bfr[2];
            #pragma unroll
            for (int i = 0; i < 2; i++) {
                int r = wm + i * 16 + l15;
                af[i] = ldfrag(&As[cur][r * 64 + (((c * 4 + quad) ^ (r & 7)) * 8)]);
            }
            #pragma unroll
            for (int j = 0; j < 2; j++) {
                int r = wn + j * 16 + l15;
                bfr[j] = ldfrag(&Bs[cur][r * 64 + (((c * 4 + quad) ^ (r & 7)) * 8)]);
            }
            #pragma unroll
            for (int i = 0; i < 2; i++)
                #pragma unroll
                for (int j = 0; j < 2; j++)
                    acc[i][j] = __builtin_amdgcn_mfma_f32_16x16x32_bf16(af[i], bfr[j], acc[i][j], 0, 0, 0);
        }
        if (pre) {
            // compiler inserts the minimal vmcnt wait for f0..f3 itself
            cvt8st(&Bs[nxt][brow * 64 + sa * 8], f0, f1);
            cvt8st(&Bs[nxt][brow * 64 + sb * 8], f2, f3);
        }
        __builtin_amdgcn_s_barrier();   // no drain: ds_writes covered by next
        cur = nxt;                      // iteration's lgkmcnt(0)+barrier
    }

    // epilogue: C layout col=lane&15, row=quad*4+r
    if (gridDim.y > 1 && z) {
        #pragma unroll
        for (int i = 0; i < 2; i++) {
            int row = m0 + wm + i * 16 + quad * 4;
            #pragma unroll
            for (int j = 0; j < 2; j++) {
                int col = n0 + wn + j * 16 + l15;
                #pragma unroll
                for (int r = 0; r < 4; r++)
                    scratch[(size_t)(row + r) * N + col] = acc[i][j][r];
            }
        }
        return;
    }
    #pragma unroll
    for (int i = 0; i < 2; i++) {
        int row = m0 + wm + i * 16 + quad * 4;
        #pragma unroll
        for (int j = 0; j < 2; j++) {
            int col = n0 + wn + j * 16 + l15;
            float bv = bias[col];
            #pragma unroll
            for (int r = 0; r < 4; r++) {
                float v = acc[i][j][r] + bv;
                if (residual) v += residual[(size_t)(row + r) * N + col];
                if (out_f32) ((float*)C)[(size_t)(row + r) * N + col] = v;
                else ((ushort_t*)C)[(size_t)(row + r) * N + col] = f2b(v);
            }
        }
    }
}

// ---------------- split-K reduction: dst += src (f32, T*HID elems) ---------
__global__ __launch_bounds__(256) void add_inplace(
    float* __restrict__ dst, const float* __restrict__ src)
{
    int i = (blockIdx.x * 256 + threadIdx.x) * 4;
    float4 a = ld16f(dst + i);
    float4 b = ld16f(src + i);
    a.x += b.x; a.y += b.y; a.z += b.z; a.w += b.w;
    __builtin_memcpy(dst + i, &a, 16);
}

// ---------------- RoPE (YaRN-style NTK) on bf16 qkv ------------------------
__global__ __launch_bounds__(256) void rope_kernel(ushort_t* __restrict__ qkv)
{
    int idx = blockIdx.x * 256 + threadIdx.x;  // T*(NH+KV)*32
    int d = idx & 31;
    int rest = idx >> 5;
    int head = rest % (NH + KV);
    int tok = rest / (NH + KV);

    // constants folded: log2(150000)=17.194638
    // low = 8.092761, high = 17.397992, conc = 1.3465736
    float fd = (float)d;
    float freq = exp2f(fd * (17.194638f / 32.0f));
    float interpolation = 1.0f / (32.0f * freq);
    float extrapolation = 1.0f / freq;
    float ramp = (fd - 8.092761f) * (1.0f / (17.397992f - 8.092761f));
    ramp = fminf(fmaxf(ramp, 0.0f), 1.0f);
    float mask = 1.0f - ramp;
    float inv_freq = interpolation * (1.0f - mask) + extrapolation * mask;
    float ang = (float)tok * inv_freq;
    float s = sinf(ang) * 1.3465736f;
    float c = cosf(ang) * 1.3465736f;

    size_t base = (head < NH)
        ? (size_t)tok * QKV_DIM + head * HD
        : (size_t)tok * QKV_DIM + NH * HD + (head - NH) * HD;
    float x1 = b2f(qkv[base + d]);
    float x2 = b2f(qkv[base + 32 + d]);
    qkv[base + d]      = f2b(x1 * c - x2 * s);
    qkv[base + 32 + d] = f2b(x2 * c + x1 * s);
}

// ---------------- Flash attention: causal GQA, one (head, 64-row Q tile) ---
__global__ __launch_bounds__(256) void attn_kernel(
    const ushort_t* __restrict__ qkv, ushort_t* __restrict__ o)
{
    const int qt = blockIdx.x;   // 0..15
    const int h  = blockIdx.y;   // 0..63
    const int g  = h >> 3;       // kv head
    const int tid = threadIdx.x;
    const int lane = tid & 63, wave = tid >> 6;
    const int l15 = lane & 15, quad = lane >> 4;

    __shared__ ushort_t Ks[64 * 72];      // K rows, padded stride 72
    __shared__ ushort_t Vt[64 * 72];      // V transposed: Vt[d][s]
    __shared__ ushort_t Ps[4][16 * 72];   // wave-private P

    bf16x8 qf[2];
    const int qrow = qt * 64 + wave * 16 + l15;
    #pragma unroll
    for (int c = 0; c < 2; c++)
        qf[c] = ldfrag(&qkv[(size_t)qrow * QKV_DIM + h * HD + quad * 8 + 32 * c]);

    floatx4 ofrag[4] = {};
    float mrow[4], lrow[4];
    #pragma unroll
    for (int r = 0; r < 4; r++) { mrow[r] = -1e30f; lrow[r] = 0.f; }

    for (int kt = 0; kt <= qt; ++kt) {
        {   // stage K (row-major, padded) and V (transposed)
            int row = tid >> 2;
            int seg = (tid & 3) * 16;
            size_t sb = (size_t)(kt * 64 + row) * QKV_DIM + NH * HD + g * HD;
            st16(&Ks[row * 72 + seg],     ld16(&qkv[sb + seg]));
            st16(&Ks[row * 72 + seg + 8], ld16(&qkv[sb + seg + 8]));
            uint4 v0 = ld16(&qkv[sb + KV * HD + seg]);
            uint4 v1 = ld16(&qkv[sb + KV * HD + seg + 8]);
            uint_t w0[4] = {v0.x, v0.y, v0.z, v0.w};
            uint_t w1[4] = {v1.x, v1.y, v1.z, v1.w};
            #pragma unroll
            for (int e = 0; e < 8; e++) {
                ushort_t s0 = (e & 1) ? (ushort_t)(w0[e >> 1] >> 16) : (ushort_t)(w0[e >> 1] & 0xffffu);
                ushort_t s1 = (e & 1) ? (ushort_t)(w1[e >> 1] >> 16) : (ushort_t)(w1[e >> 1] & 0xffffu);
                Vt[(seg + e) * 72 + row]     = s0;
                Vt[(seg + 8 + e) * 72 + row] = s1;
            }
        }
        __syncthreads();

        // S = Q K^T (scaled); C layout row=quad*4+r (query), col=lane&15 (key)
        floatx4 sf[4];
        #pragma unroll
        for (int j = 0; j < 4; j++) {
            floatx4 z = {};
            #pragma unroll
            for (int c = 0; c < 2; c++) {
                bf16x8 kf = ldfrag(&Ks[(j * 16 + l15) * 72 + quad * 8 + 32 * c]);
                z = __builtin_amdgcn_mfma_f32_16x16x32_bf16(qf[c], kf, z, 0, 0, 0);
            }
            sf[j] = z;
        }
        const int qg = qt * 64 + wave * 16 + quad * 4;
        const int kgb = kt * 64 + l15;
        float rowmax[4];
        #pragma unroll
        for (int r = 0; r < 4; r++) rowmax[r] = -1e30f;
        #pragma unroll
        for (int j = 0; j < 4; j++)
            #pragma unroll
            for (int r = 0; r < 4; r++) {
                float v = sf[j][r] * 0.125f;
                if (kgb + j * 16 > qg + r) v = -1e30f;
                sf[j][r] = v;
                rowmax[r] = fmaxf(rowmax[r], v);
            }
        #pragma unroll
        for (int r = 0; r < 4; r++)
            #pragma unroll
            for (int m = 1; m < 16; m <<= 1)
                rowmax[r] = fmaxf(rowmax[r], __shfl_xor(rowmax[r], m, 64));
        float alpha[4], rowsum[4];
        #pragma unroll
        for (int r = 0; r < 4; r++) {
            float mnew = fmaxf(mrow[r], rowmax[r]);
            alpha[r] = __expf(mrow[r] - mnew);
            mrow[r] = mnew;
            rowsum[r] = 0.f;
        }
        #pragma unroll
        for (int j = 0; j < 4; j++)
            #pragma unroll
            for (int r = 0; r < 4; r++) {
                float p = __expf(sf[j][r] - mrow[r]);
                rowsum[r] += p;
                Ps[wave][(quad * 4 + r) * 72 + j * 16 + l15] = f2b(p);
            }
        #pragma unroll
        for (int r = 0; r < 4; r++) {
            #pragma unroll
            for (int m = 1; m < 16; m <<= 1)
                rowsum[r] += __shfl_xor(rowsum[r], m, 64);
            lrow[r] = lrow[r] * alpha[r] + rowsum[r];
        }
        #pragma unroll
        for (int j = 0; j < 4; j++)
            #pragma unroll
            for (int r = 0; r < 4; r++)
                ofrag[j][r] *= alpha[r];
        __syncthreads();   // Ps visible before A-layout reads
        #pragma unroll
        for (int c = 0; c < 2; c++) {
            bf16x8 pf = ldfrag(&Ps[wave][l15 * 72 + quad * 8 + 32 * c]);
            #pragma unroll
            for (int j = 0; j < 4; j++) {
                bf16x8 vf = ldfrag(&Vt[(j * 16 + l15) * 72 + quad * 8 + 32 * c]);
                ofrag[j] = __builtin_amdgcn_mfma_f32_16x16x32_bf16(pf, vf, ofrag[j], 0, 0, 0);
            }
        }
        __syncthreads();
    }
    #pragma unroll
    for (int j = 0; j < 4; j++)
        #pragma unroll
        for (int r = 0; r < 4; r++) {
            int row = qt * 64 + wave * 16 + quad * 4 + r;
            int col = h * HD + j * 16 + l15;
            o[(size_t)row * O_DIM + col] = f2b(ofrag[j][r] / lrow[r]);
        }
}

// ---------------- gated activation: u bf16 [T,2I] -> ac bf16 [T,I] ---------
__global__ __launch_bounds__(256) void act_kernel(
    const ushort_t* __restrict__ u, ushort_t* __restrict__ act)
{
    int i = blockIdx.x * 256 + threadIdx.x;
    if (i >= T_TOK * INTER) return;
    int row = i / INTER, c = i % INTER;
    uint_t v; __builtin_memcpy(&v, u + (size_t)row * (2 * INTER) + 2 * c, 4);
    float gt  = b2f((ushort_t)(v & 0xffffu));
    float lin = b2f((ushort_t)(v >> 16));
    gt = fminf(gt, 7.0f);
    lin = fminf(fmaxf(lin, -7.0f), 7.0f);
    float sg = 1.0f / (1.0f + __expf(-1.702f * gt));
    act[i] = f2b(gt * sg * (lin + 1.0f));
}

extern "C" void kernel_launch(void* const* d_in, const int* in_sizes, int n_in,
                              void* d_out, int out_size, void* d_ws, size_t ws_size,
                              hipStream_t stream)
{
    const float* x               = (const float*)d_in[0];
    const float* attn_norm_scale = (const float*)d_in[1];
    const float* wqkv            = (const float*)d_in[2];
    const float* bqkv            = (const float*)d_in[3];
    const float* wout            = (const float*)d_in[4];
    const float* bout            = (const float*)d_in[5];
    const float* mlp_norm_scale  = (const float*)d_in[6];
    const float* w1              = (const float*)d_in[7];
    const float* b1              = (const float*)d_in[8];
    const float* w2              = (const float*)d_in[9];
    const float* b2              = (const float*)d_in[10];
    float* out = (float*)d_out;

    // ws (bf16 buffers, total 42.5 MB < proven 49.5):
    // [t 5.9][qkv 10.49][ob 8.39][u 11.8][ac 5.9]; h lives in d_out (f32).
    // Scratch reuse for split-K partials (f32, 11.8 MB = T*HID*4):
    //   wout partial -> u region (written by w1 only AFTER the reduce)
    //   w2 partial   -> qkv+ob region (dead after attn/wout)
    char* ws = (char*)d_ws;
    ushort_t* t   = (ushort_t*)ws;                               // T*HID
    ushort_t* qkv = (ushort_t*)(ws + (size_t)T_TOK * HID * 2);
    ushort_t* ob  = (ushort_t*)(ws + (size_t)T_TOK * (HID + QKV_DIM) * 2);
    ushort_t* u   = (ushort_t*)(ws + (size_t)T_TOK * (HID + QKV_DIM + O_DIM) * 2);
    ushort_t* ac  = (ushort_t*)(ws + (size_t)T_TOK * (HID + QKV_DIM + O_DIM + 2 * INTER) * 2);
    float* sc1 = (float*)u;      // wout split-K partial
    float* sc2 = (float*)qkv;    // w2 split-K partial

    rmsnorm_f2b<<<T_TOK, 256, 0, stream>>>(x, attn_norm_scale, t);
    gemm_bt<<<dim3((T_TOK / 64) * (QKV_DIM / 64)), 256, 0, stream>>>(
        t, wqkv, bqkv, nullptr, qkv, 0, nullptr, T_TOK, QKV_DIM, HID);
    rope_kernel<<<(T_TOK * (NH + KV) * 32) / 256, 256, 0, stream>>>(qkv);
    attn_kernel<<<dim3(T_TOK / 64, NH), 256, 0, stream>>>(qkv, ob);
    gemm_bt<<<dim3((T_TOK / 64) * (HID / 64), 2), 256, 0, stream>>>(
        ob, wout, bout, x, out, 1, sc1, T_TOK, HID, O_DIM);      // h -> d_out
    add_inplace<<<(T_TOK * HID) / 1024, 256, 0, stream>>>(out, sc1);
    rmsnorm_f2b<<<T_TOK, 256, 0, stream>>>(out, mlp_norm_scale, t);
    gemm_bt<<<dim3((T_TOK / 64) * ((2 * INTER) / 64)), 256, 0, stream>>>(
        t, w1, b1, nullptr, u, 0, nullptr, T_TOK, 2 * INTER, HID);
    act_kernel<<<(T_TOK * INTER + 255) / 256, 256, 0, stream>>>(u, ac);
    gemm_bt<<<dim3((T_TOK / 64) * (HID / 64), 2), 256, 0, stream>>>(
        ac, w2, b2, out, out, 1, sc2, T_TOK, HID, INTER);        // in-place residual
    add_inplace<<<(T_TOK * HID) / 1024, 256, 0, stream>>>(out, sc2);
}

// Round 7
// 535.996 us; speedup vs baseline: 1.1846x; 1.1846x over previous
//
#include <hip/hip_runtime.h>

typedef unsigned short ushort_t;
typedef unsigned int uint_t;
typedef __bf16 bf16x8 __attribute__((ext_vector_type(8)));
typedef float floatx4 __attribute__((ext_vector_type(4)));

#define T_TOK 1024
#define HID 2880
#define NH 64
#define KV 8
#define HD 64
#define INTER 2880
#define QKV_DIM 5120   // HD*(NH+2*KV)
#define O_DIM 4096     // NH*HD

typedef __attribute__((address_space(1))) const uint_t glb_u32;
typedef __attribute__((address_space(3))) uint_t lds_u32;

__device__ __forceinline__ float b2f(ushort_t u) {
    uint_t i = ((uint_t)u) << 16;
    return __builtin_bit_cast(float, i);
}
__device__ __forceinline__ ushort_t f2b(float f) {
    uint_t i = __builtin_bit_cast(uint_t, f);
    uint_t r = i + 0x7FFFu + ((i >> 16) & 1u);
    return (ushort_t)(r >> 16);
}
__device__ __forceinline__ uint4 ld16(const void* p) { uint4 v; __builtin_memcpy(&v, p, 16); return v; }
__device__ __forceinline__ void st16(void* p, uint4 v) { __builtin_memcpy(p, &v, 16); }
__device__ __forceinline__ float4 ld16f(const void* p) { float4 v; __builtin_memcpy(&v, p, 16); return v; }
__device__ __forceinline__ bf16x8 ldfrag(const void* p) { bf16x8 v; __builtin_memcpy(&v, p, 16); return v; }
// native bf16 casts -> v_cvt_pk_bf16_f32 (RNE, bit-identical to the f2b trick)
__device__ __forceinline__ void cvt8st(void* lds, float4 a, float4 b) {
    __bf16 o[8] = {(__bf16)a.x, (__bf16)a.y, (__bf16)a.z, (__bf16)a.w,
                   (__bf16)b.x, (__bf16)b.y, (__bf16)b.z, (__bf16)b.w};
    __builtin_memcpy(lds, o, 16);
}

// ---------------- RMSNorm: f32 in -> bf16 out ------------------------------
__global__ __launch_bounds__(256) void rmsnorm_f2b(
    const float* __restrict__ x, const float* __restrict__ scale,
    ushort_t* __restrict__ out)
{
    const int row = blockIdx.x;
    const int tid = threadIdx.x;
    const float* xr = x + (size_t)row * HID;
    float ss = 0.f;
    for (int i = tid; i < HID / 4; i += 256) {
        float4 v = ld16f(xr + i * 4);
        ss += v.x * v.x + v.y * v.y + v.z * v.z + v.w * v.w;
    }
    #pragma unroll
    for (int m = 32; m >= 1; m >>= 1) ss += __shfl_xor(ss, m, 64);
    __shared__ float red[4];
    if ((tid & 63) == 0) red[tid >> 6] = ss;
    __syncthreads();
    float rstd = rsqrtf((red[0] + red[1] + red[2] + red[3]) / (float)HID + 1e-5f);
    for (int i = tid; i < HID / 8; i += 256) {
        float4 a = ld16f(xr + i * 8);
        float4 b = ld16f(xr + i * 8 + 4);
        float4 sa = ld16f(scale + i * 8);
        float4 sb = ld16f(scale + i * 8 + 4);
        cvt8st(out + (size_t)row * HID + i * 8,
               make_float4(a.x * rstd * sa.x, a.y * rstd * sa.y, a.z * rstd * sa.z, a.w * rstd * sa.w),
               make_float4(b.x * rstd * sb.x, b.y * rstd * sb.y, b.z * rstd * sb.z, b.w * rstd * sb.w));
    }
}

// ---------------- GEMM: C[M,N] = A_bf16[M,K] @ B_f32[N,K]^T + bias ---------
// BM=128, BN=64, BK=64, 256 threads (2x2 waves, wave tile 64x32).
// R4 structure with DEPTH-2 B prefetch: B(kt+2)'s f32 loads are issued at
// iter kt and converted/ds-written at iter kt+1 from registers -- the
// cvt8st never waits on a fresh load (R4's hidden per-step stall: B loads
// issued and consumed inside the same barrier interval). Counted vmcnt at
// the top retires exactly the 8 one-iteration-old ops (4 glds A + 4 B f32),
// never fresh ones. glds A stays 1-ahead (A is L2/L3-resident activations;
// B is the 47-66MB weight stream needing 2 iterations of cover).
// XOR-swizzled LDS (slot ^= row&7); A's glds source pre-swizzled.
// N-MAJOR tile order (B panel shared by consecutive blocks -> L2 hit) +
// bijective XCD chunking. Optional split-K (gridDim.y==2): z=1 writes raw
// f32 partial to scratch; add_inplace reduces.
__global__ __launch_bounds__(256) void gemm_bt(
    const ushort_t* __restrict__ A, const float* __restrict__ B,
    const float* __restrict__ bias, const float* residual,
    void* C, int out_f32, float* __restrict__ scratch,
    int M, int N, int K)
{
    __shared__ ushort_t As[2][128 * 64];   // 2 x 16 KB
    __shared__ ushort_t Bs[2][64 * 64];    // 2 x 8 KB
    const int tid = threadIdx.x;
    const int lane = tid & 63, wave = tid >> 6;
    const int l15 = lane & 15, quad = lane >> 4;

    // XCD-aware bijective remap: XCD k owns a contiguous chunk of flats.
    const int nbm = M >> 7;
    int flat = (int)blockIdx.x;
    const int cpx = (int)gridDim.x >> 3;
    flat = (flat & 7) * cpx + (flat >> 3);
    // n-major decode: consecutive flats share the B panel (n0), vary m0.
    const int m0 = (flat % nbm) * 128;
    const int n0 = (flat / nbm) * 64;

    const int wm = (wave >> 1) * 64, wn = (wave & 1) * 32;

    // split-K bounds (by 64-wide K-steps; handles nk odd)
    const int z = (int)blockIdx.y;
    const int nk_all = K >> 6;
    const int nk0 = (nk_all + 1) >> 1;
    const int kbeg = (gridDim.y > 1 && z) ? (nk0 << 6) : 0;
    const int nk = (gridDim.y > 1) ? (z ? nk_all - nk0 : nk0) : nk_all;

    // A glds: lane l of wave w, instr q -> LDS row w*32+q*8+(l>>3), slot l&7.
    // row&7 == l>>3, so the swizzled global slot is constant per lane:
    const int arow = wave * 32 + (lane >> 3);          // + q*8
    const int aslot = (lane & 7) ^ (lane >> 3);
    const ushort_t* Abase = A + (size_t)(m0 + arow) * K + kbeg + aslot * 8;

    // B staging: thread t -> row t>>2, k-slots (t&3) and (t&3)+4
    const int brow = tid >> 2;
    const int kb = (tid & 3) * 8;
    const int sa = (tid & 3) ^ (brow & 7);
    const int sb = ((tid & 3) + 4) ^ (brow & 7);
    const float* Bbase = B + (size_t)(n0 + brow) * K + kbeg;

    floatx4 acc[4][2] = {};

    // ---- prologue: B(0) -> regs -> Bs[0]; glds A(0) -> As[0]; B(1) -> regs
    float4 f0 = ld16f(Bbase + kb);
    float4 f1 = ld16f(Bbase + kb + 4);
    float4 f2 = ld16f(Bbase + kb + 32);
    float4 f3 = ld16f(Bbase + kb + 36);
    #pragma unroll
    for (int q = 0; q < 4; q++)
        __builtin_amdgcn_global_load_lds(
            (glb_u32*)(Abase + (size_t)(q * 8) * K),
            (lds_u32*)(&As[0][(wave * 4 + q) * 512]), 16, 0, 0);
    cvt8st(&Bs[0][brow * 64 + sa * 8], f0, f1);   // waits B(0); glds stay
    cvt8st(&Bs[0][brow * 64 + sb * 8], f2, f3);
    if (nk > 1) {
        f0 = ld16f(Bbase + 64 + kb);
        f1 = ld16f(Bbase + 64 + kb + 4);
        f2 = ld16f(Bbase + 64 + kb + 32);
        f3 = ld16f(Bbase + 64 + kb + 36);
    }
    // loop-entry invariant: outstanding = glds A(kt) x4 (older) + B(kt+1) x4

    int cur = 0;
    for (int kt = 0; kt < nk; ++kt) {
        const int nxt = cur ^ 1;
        const bool preA = (kt + 1 < nk);
        const bool preB = (kt + 2 < nk);
        float4 g0, g1, g2, g3;
        if (preA) {
            const int k1 = (kt + 1) << 6;
            #pragma unroll
            for (int q = 0; q < 4; q++)
                __builtin_amdgcn_global_load_lds(
                    (glb_u32*)(Abase + (size_t)(q * 8) * K + k1),
                    (lds_u32*)(&As[nxt][(wave * 4 + q) * 512]), 16, 0, 0);
        }
        if (preB) {
            const int k2 = (kt + 2) << 6;
            g0 = ld16f(Bbase + k2 + kb);
            g1 = ld16f(Bbase + k2 + kb + 4);
            g2 = ld16f(Bbase + k2 + kb + 32);
            g3 = ld16f(Bbase + k2 + kb + 36);
        }
        // retire exactly the one-iteration-old ops; fresh ones stay in flight
        if (preB)      asm volatile("s_waitcnt vmcnt(8)" ::: "memory");
        else if (preA) asm volatile("s_waitcnt vmcnt(4)" ::: "memory");
        else           asm volatile("s_waitcnt vmcnt(0)" ::: "memory");
        asm volatile("s_waitcnt lgkmcnt(0)" ::: "memory");
        __builtin_amdgcn_s_barrier();
        __builtin_amdgcn_sched_barrier(0);   // pin: no ds_read above barrier

        // ---- compute on buffer cur (next-tile loads in flight)
        #pragma unroll
        for (int c = 0; c < 2; c++) {
            bf16x8 af[4], bfr[2];
            #pragma unroll
            for (int i = 0; i < 4; i++) {
                int r = wm + i * 16 + l15;
                af[i] = ldfrag(&As[cur][r * 64 + (((c * 4 + quad) ^ (r & 7)) * 8)]);
            }
            #pragma unroll
            for (int j = 0; j < 2; j++) {
                int r = wn + j * 16 + l15;
                bfr[j] = ldfrag(&Bs[cur][r * 64 + (((c * 4 + quad) ^ (r & 7)) * 8)]);
            }
            #pragma unroll
            for (int i = 0; i < 4; i++)
                #pragma unroll
                for (int j = 0; j < 2; j++)
                    acc[i][j] = __builtin_amdgcn_mfma_f32_16x16x32_bf16(af[i], bfr[j], acc[i][j], 0, 0, 0);
        }
        if (preA) {
            // B(kt+1) regs were retired by the counted vmcnt -- no wait here
            cvt8st(&Bs[nxt][brow * 64 + sa * 8], f0, f1);
            cvt8st(&Bs[nxt][brow * 64 + sb * 8], f2, f3);
            if (preB) { f0 = g0; f1 = g1; f2 = g2; f3 = g3; }
        }
        __builtin_amdgcn_s_barrier();   // protects As[nxt] glds vs readers
        cur = nxt;
    }

    // epilogue: C layout col=lane&15, row=quad*4+r
    if (gridDim.y > 1 && z) {
        #pragma unroll
        for (int i = 0; i < 4; i++) {
            int row = m0 + wm + i * 16 + quad * 4;
            #pragma unroll
            for (int j = 0; j < 2; j++) {
                int col = n0 + wn + j * 16 + l15;
                #pragma unroll
                for (int r = 0; r < 4; r++)
                    scratch[(size_t)(row + r) * N + col] = acc[i][j][r];
            }
        }
        return;
    }
    #pragma unroll
    for (int i = 0; i < 4; i++) {
        int row = m0 + wm + i * 16 + quad * 4;
        #pragma unroll
        for (int j = 0; j < 2; j++) {
            int col = n0 + wn + j * 16 + l15;
            float bv = bias[col];
            #pragma unroll
            for (int r = 0; r < 4; r++) {
                float v = acc[i][j][r] + bv;
                if (residual) v += residual[(size_t)(row + r) * N + col];
                if (out_f32) ((float*)C)[(size_t)(row + r) * N + col] = v;
                else ((ushort_t*)C)[(size_t)(row + r) * N + col] = f2b(v);
            }
        }
    }
}

// ---------------- split-K reduction: dst += src (f32, T*HID elems) ---------
__global__ __launch_bounds__(256) void add_inplace(
    float* __restrict__ dst, const float* __restrict__ src)
{
    int i = (blockIdx.x * 256 + threadIdx.x) * 4;
    float4 a = ld16f(dst + i);
    float4 b = ld16f(src + i);
    a.x += b.x; a.y += b.y; a.z += b.z; a.w += b.w;
    __builtin_memcpy(dst + i, &a, 16);
}

// ---------------- RoPE (YaRN-style NTK) on bf16 qkv ------------------------
__global__ __launch_bounds__(256) void rope_kernel(ushort_t* __restrict__ qkv)
{
    int idx = blockIdx.x * 256 + threadIdx.x;  // T*(NH+KV)*32
    int d = idx & 31;
    int rest = idx >> 5;
    int head = rest % (NH + KV);
    int tok = rest / (NH + KV);

    // constants folded: log2(150000)=17.194638
    // low = 8.092761, high = 17.397992, conc = 1.3465736
    float fd = (float)d;
    float freq = exp2f(fd * (17.194638f / 32.0f));
    float interpolation = 1.0f / (32.0f * freq);
    float extrapolation = 1.0f / freq;
    float ramp = (fd - 8.092761f) * (1.0f / (17.397992f - 8.092761f));
    ramp = fminf(fmaxf(ramp, 0.0f), 1.0f);
    float mask = 1.0f - ramp;
    float inv_freq = interpolation * (1.0f - mask) + extrapolation * mask;
    float ang = (float)tok * inv_freq;
    float s = sinf(ang) * 1.3465736f;
    float c = cosf(ang) * 1.3465736f;

    size_t base = (head < NH)
        ? (size_t)tok * QKV_DIM + head * HD
        : (size_t)tok * QKV_DIM + NH * HD + (head - NH) * HD;
    float x1 = b2f(qkv[base + d]);
    float x2 = b2f(qkv[base + 32 + d]);
    qkv[base + d]      = f2b(x1 * c - x2 * s);
    qkv[base + 32 + d] = f2b(x2 * c + x1 * s);
}

// ---------------- Flash attention: causal GQA, one (head, 64-row Q tile) ---
__global__ __launch_bounds__(256) void attn_kernel(
    const ushort_t* __restrict__ qkv, ushort_t* __restrict__ o)
{
    const int qt = blockIdx.x;   // 0..15
    const int h  = blockIdx.y;   // 0..63
    const int g  = h >> 3;       // kv head
    const int tid = threadIdx.x;
    const int lane = tid & 63, wave = tid >> 6;
    const int l15 = lane & 15, quad = lane >> 4;

    __shared__ ushort_t Ks[64 * 72];      // K rows, padded stride 72
    __shared__ ushort_t Vt[64 * 72];      // V transposed: Vt[d][s]
    __shared__ ushort_t Ps[4][16 * 72];   // wave-private P

    bf16x8 qf[2];
    const int qrow = qt * 64 + wave * 16 + l15;
    #pragma unroll
    for (int c = 0; c < 2; c++)
        qf[c] = ldfrag(&qkv[(size_t)qrow * QKV_DIM + h * HD + quad * 8 + 32 * c]);

    floatx4 ofrag[4] = {};
    float mrow[4], lrow[4];
    #pragma unroll
    for (int r = 0; r < 4; r++) { mrow[r] = -1e30f; lrow[r] = 0.f; }

    for (int kt = 0; kt <= qt; ++kt) {
        {   // stage K (row-major, padded) and V (transposed)
            int row = tid >> 2;
            int seg = (tid & 3) * 16;
            size_t sb = (size_t)(kt * 64 + row) * QKV_DIM + NH * HD + g * HD;
            st16(&Ks[row * 72 + seg],     ld16(&qkv[sb + seg]));
            st16(&Ks[row * 72 + seg + 8], ld16(&qkv[sb + seg + 8]));
            uint4 v0 = ld16(&qkv[sb + KV * HD + seg]);
            uint4 v1 = ld16(&qkv[sb + KV * HD + seg + 8]);
            uint_t w0[4] = {v0.x, v0.y, v0.z, v0.w};
            uint_t w1[4] = {v1.x, v1.y, v1.z, v1.w};
            #pragma unroll
            for (int e = 0; e < 8; e++) {
                ushort_t s0 = (e & 1) ? (ushort_t)(w0[e >> 1] >> 16) : (ushort_t)(w0[e >> 1] & 0xffffu);
                ushort_t s1 = (e & 1) ? (ushort_t)(w1[e >> 1] >> 16) : (ushort_t)(w1[e >> 1] & 0xffffu);
                Vt[(seg + e) * 72 + row]     = s0;
                Vt[(seg + 8 + e) * 72 + row] = s1;
            }
        }
        __syncthreads();

        // S = Q K^T (scaled); C layout row=quad*4+r (query), col=lane&15 (key)
        floatx4 sf[4];
        #pragma unroll
        for (int j = 0; j < 4; j++) {
            floatx4 z = {};
            #pragma unroll
            for (int c = 0; c < 2; c++) {
                bf16x8 kf = ldfrag(&Ks[(j * 16 + l15) * 72 + quad * 8 + 32 * c]);
                z = __builtin_amdgcn_mfma_f32_16x16x32_bf16(qf[c], kf, z, 0, 0, 0);
            }
            sf[j] = z;
        }
        const int qg = qt * 64 + wave * 16 + quad * 4;
        const int kgb = kt * 64 + l15;
        float rowmax[4];
        #pragma unroll
        for (int r = 0; r < 4; r++) rowmax[r] = -1e30f;
        #pragma unroll
        for (int j = 0; j < 4; j++)
            #pragma unroll
            for (int r = 0; r < 4; r++) {
                float v = sf[j][r] * 0.125f;
                if (kgb + j * 16 > qg + r) v = -1e30f;
                sf[j][r] = v;
                rowmax[r] = fmaxf(rowmax[r], v);
            }
        #pragma unroll
        for (int r = 0; r < 4; r++)
            #pragma unroll
            for (int m = 1; m < 16; m <<= 1)
                rowmax[r] = fmaxf(rowmax[r], __shfl_xor(rowmax[r], m, 64));
        float alpha[4], rowsum[4];
        #pragma unroll
        for (int r = 0; r < 4; r++) {
            float mnew = fmaxf(mrow[r], rowmax[r]);
            alpha[r] = __expf(mrow[r] - mnew);
            mrow[r] = mnew;
            rowsum[r] = 0.f;
        }
        #pragma unroll
        for (int j = 0; j < 4; j++)
            #pragma unroll
            for (int r = 0; r < 4; r++) {
                float p = __expf(sf[j][r] - mrow[r]);
                rowsum[r] += p;
                Ps[wave][(quad * 4 + r) * 72 + j * 16 + l15] = f2b(p);
            }
        #pragma unroll
        for (int r = 0; r < 4; r++) {
            #pragma unroll
            for (int m = 1; m < 16; m <<= 1)
                rowsum[r] += __shfl_xor(rowsum[r], m, 64);
            lrow[r] = lrow[r] * alpha[r] + rowsum[r];
        }
        #pragma unroll
        for (int j = 0; j < 4; j++)
            #pragma unroll
            for (int r = 0; r < 4; r++)
                ofrag[j][r] *= alpha[r];
        __syncthreads();   // Ps visible before A-layout reads
        #pragma unroll
        for (int c = 0; c < 2; c++) {
            bf16x8 pf = ldfrag(&Ps[wave][l15 * 72 + quad * 8 + 32 * c]);
            #pragma unroll
            for (int j = 0; j < 4; j++) {
                bf16x8 vf = ldfrag(&Vt[(j * 16 + l15) * 72 + quad * 8 + 32 * c]);
                ofrag[j] = __builtin_amdgcn_mfma_f32_16x16x32_bf16(pf, vf, ofrag[j], 0, 0, 0);
            }
        }
        __syncthreads();
    }
    #pragma unroll
    for (int j = 0; j < 4; j++)
        #pragma unroll
        for (int r = 0; r < 4; r++) {
            int row = qt * 64 + wave * 16 + quad * 4 + r;
            int col = h * HD + j * 16 + l15;
            o[(size_t)row * O_DIM + col] = f2b(ofrag[j][r] / lrow[r]);
        }
}

// ---------------- gated activation: u bf16 [T,2I] -> ac bf16 [T,I] ---------
__global__ __launch_bounds__(256) void act_kernel(
    const ushort_t* __restrict__ u, ushort_t* __restrict__ act)
{
    int i = blockIdx.x * 256 + threadIdx.x;
    if (i >= T_TOK * INTER) return;
    int row = i / INTER, c = i % INTER;
    uint_t v; __builtin_memcpy(&v, u + (size_t)row * (2 * INTER) + 2 * c, 4);
    float gt  = b2f((ushort_t)(v & 0xffffu));
    float lin = b2f((ushort_t)(v >> 16));
    gt = fminf(gt, 7.0f);
    lin = fminf(fmaxf(lin, -7.0f), 7.0f);
    float sg = 1.0f / (1.0f + __expf(-1.702f * gt));
    act[i] = f2b(gt * sg * (lin + 1.0f));
}

extern "C" void kernel_launch(void* const* d_in, const int* in_sizes, int n_in,
                              void* d_out, int out_size, void* d_ws, size_t ws_size,
                              hipStream_t stream)
{
    const float* x               = (const float*)d_in[0];
    const float* attn_norm_scale = (const float*)d_in[1];
    const float* wqkv            = (const float*)d_in[2];
    const float* bqkv            = (const float*)d_in[3];
    const float* wout            = (const float*)d_in[4];
    const float* bout            = (const float*)d_in[5];
    const float* mlp_norm_scale  = (const float*)d_in[6];
    const float* w1              = (const float*)d_in[7];
    const float* b1              = (const float*)d_in[8];
    const float* w2              = (const float*)d_in[9];
    const float* b2              = (const float*)d_in[10];
    float* out = (float*)d_out;

    // ws (bf16 buffers, total 42.5 MB < proven 49.5):
    // [t 5.9][qkv 10.49][ob 8.39][u 11.8][ac 5.9]; h lives in d_out (f32).
    // Scratch reuse for split-K partials (f32, 11.8 MB = T*HID*4):
    //   wout partial -> u region (written by w1 only AFTER the reduce)
    //   w2 partial   -> qkv+ob region (dead after attn/wout)
    char* ws = (char*)d_ws;
    ushort_t* t   = (ushort_t*)ws;                               // T*HID
    ushort_t* qkv = (ushort_t*)(ws + (size_t)T_TOK * HID * 2);
    ushort_t* ob  = (ushort_t*)(ws + (size_t)T_TOK * (HID + QKV_DIM) * 2);
    ushort_t* u   = (ushort_t*)(ws + (size_t)T_TOK * (HID + QKV_DIM + O_DIM) * 2);
    ushort_t* ac  = (ushort_t*)(ws + (size_t)T_TOK * (HID + QKV_DIM + O_DIM + 2 * INTER) * 2);
    float* sc1 = (float*)u;      // wout split-K partial
    float* sc2 = (float*)qkv;    // w2 split-K partial

    rmsnorm_f2b<<<T_TOK, 256, 0, stream>>>(x, attn_norm_scale, t);
    gemm_bt<<<dim3((T_TOK / 128) * (QKV_DIM / 64)), 256, 0, stream>>>(
        t, wqkv, bqkv, nullptr, qkv, 0, nullptr, T_TOK, QKV_DIM, HID);
    rope_kernel<<<(T_TOK * (NH + KV) * 32) / 256, 256, 0, stream>>>(qkv);
    attn_kernel<<<dim3(T_TOK / 64, NH), 256, 0, stream>>>(qkv, ob);
    gemm_bt<<<dim3((T_TOK / 128) * (HID / 64), 2), 256, 0, stream>>>(
        ob, wout, bout, x, out, 1, sc1, T_TOK, HID, O_DIM);      // h -> d_out
    add_inplace<<<(T_TOK * HID) / 1024, 256, 0, stream>>>(out, sc1);
    rmsnorm_f2b<<<T_TOK, 256, 0, stream>>>(out, mlp_norm_scale, t);
    gemm_bt<<<dim3((T_TOK / 128) * ((2 * INTER) / 64)), 256, 0, stream>>>(
        t, w1, b1, nullptr, u, 0, nullptr, T_TOK, 2 * INTER, HID);
    act_kernel<<<(T_TOK * INTER + 255) / 256, 256, 0, stream>>>(u, ac);
    gemm_bt<<<dim3((T_TOK / 128) * (HID / 64), 2), 256, 0, stream>>>(
        ac, w2, b2, out, out, 1, sc2, T_TOK, HID, INTER);        // in-place residual
    add_inplace<<<(T_TOK * HID) / 1024, 256, 0, stream>>>(out, sc2);
}